// Round 3
// baseline (3092.984 us; speedup 1.0000x reference)
//
#include <hip/hip_runtime.h>

#define NN 50000
#define NE 800000

typedef __attribute__((ext_vector_type(8))) short short8;
typedef __attribute__((ext_vector_type(4))) float f32x4;

__device__ __forceinline__ float silu_f(float v) {
    return v / (1.0f + __expf(-v));
}
__device__ __forceinline__ unsigned short f2bf(float f) {
    unsigned u = __float_as_uint(f);
    u += 0x7fffu + ((u >> 16) & 1u);        // round-to-nearest-even
    return (unsigned short)(u >> 16);
}
__device__ __forceinline__ unsigned pk2(float a, float b) {
    return (unsigned)f2bf(a) | ((unsigned)f2bf(b) << 16);
}

// ---------------- prep: d2 per edge, degree per node ----------------
__global__ __launch_bounds__(256) void egnn_prep(
    const int* __restrict__ src, const int* __restrict__ dst,
    const float* __restrict__ pos,
    float* __restrict__ d2, float* __restrict__ deg)
{
    int e = blockIdx.x * 256 + threadIdx.x;
    if (e >= NE) return;
    int s = src[e], d = dst[e];
    float rx = pos[3*d+0] - pos[3*s+0];
    float ry = pos[3*d+1] - pos[3*s+1];
    float rz = pos[3*d+2] - pos[3*s+2];
    d2[e] = rx*rx + ry*ry + rz*rz;
    atomicAdd(&deg[d], 1.0f);
}

// ---------------- weight prep: transpose + bf16-convert edge weights ----------------
// Wg1[l][n][k(136)] = We1[l][k][n]  (k<128; row 128 stays fp32 in We1)
// Wg2[l][n][h(72)]  = We2[l][h][n]
__global__ __launch_bounds__(256) void egnn_prep_w(
    const float* __restrict__ We1, const float* __restrict__ We2,
    unsigned short* __restrict__ Wg1, unsigned short* __restrict__ Wg2)
{
    int i = blockIdx.x * 256 + threadIdx.x;
    if (i < 4 * 64 * 128) {
        int k = i & 127, n = (i >> 7) & 63, l = i >> 13;
        Wg1[(size_t)(l * 64 + n) * 136 + k] = f2bf(We1[((size_t)l * 129 + k) * 64 + n]);
    }
    if (i < 4 * 64 * 64) {
        int h = i & 63, n = (i >> 6) & 63, l = i >> 12;
        Wg2[(size_t)(l * 64 + n) * 72 + h] = f2bf(We2[((size_t)l * 64 + h) * 64 + n]);
    }
}

// ---------------- edge MLP via bf16 MFMA + fp32 scatter ----------------
// 64 edges/block, 4 waves. Wave w: edge-half eh=w>>1 (32 edges), col-half ch=w&1 (32 out ch).
// Computes D^T = (W^T)(x^T) so each lane owns a fixed edge (col=lane&15) per tile.
template<bool POS>
__global__ __launch_bounds__(256) void egnn_edge(
    const float* __restrict__ x, const float* __restrict__ d2v,
    const int* __restrict__ src, const int* __restrict__ dst,
    const float* __restrict__ pos,
    const unsigned short* __restrict__ Wg1, const unsigned short* __restrict__ Wg2,
    const float* __restrict__ We1,   // fp32, for d2 row (row 128)
    const float* __restrict__ be1, const float* __restrict__ be2,
    const float* __restrict__ Wp1, const float* __restrict__ bp1,
    const float* __restrict__ Wp2, const float* __restrict__ bp2,
    float* __restrict__ agg, float* __restrict__ dpos, int layer)
{
    __shared__ __align__(16) unsigned short xls[64 * 136];  // [e][k] bf16, k: 0-63 dst, 64-127 src
    __shared__ __align__(16) unsigned short m1l[64 * 72];   // [e][h] bf16
    __shared__ int   sSrc[64];
    __shared__ int   sDst[64];
    __shared__ float sD2[64];
    __shared__ float sC[64];

    const int t    = threadIdx.x;
    const int lane = t & 63;
    const int w    = t >> 6;
    const int l15  = lane & 15;
    const int g    = lane >> 4;
    const int eh   = w >> 1;
    const int ch   = w & 1;
    const int base = blockIdx.x * 64;

    if (t < 64) {
        sSrc[t] = src[base + t];
        sDst[t] = dst[base + t];
        sD2[t]  = d2v[base + t];
        if (POS) sC[t] = bp2[layer];
    }
    __syncthreads();

    // ---- gather + bf16-convert x[dst] || x[src] into xls ----
    {
        int e = t >> 2, q = t & 3;
        const float4* pd = (const float4*)&x[(size_t)sDst[e] * 64 + q * 16];
        const float4* ps = (const float4*)&x[(size_t)sSrc[e] * 64 + q * 16];
        unsigned short* row = &xls[e * 136];
        #pragma unroll
        for (int i2 = 0; i2 < 4; ++i2) {
            float4 v = pd[i2];
            *(uint2*)&row[q * 16 + i2 * 4] = make_uint2(pk2(v.x, v.y), pk2(v.z, v.w));
        }
        #pragma unroll
        for (int i2 = 0; i2 < 4; ++i2) {
            float4 v = ps[i2];
            *(uint2*)&row[64 + q * 16 + i2 * 4] = make_uint2(pk2(v.x, v.y), pk2(v.z, v.w));
        }
    }
    __syncthreads();

    // ---- GEMM1: D^T[n][e] = sum_k W1[k][n] * cat[e][k], K=128 ----
    const f32x4 zero = {0.f, 0.f, 0.f, 0.f};
    f32x4 a00 = zero, a01 = zero, a10 = zero, a11 = zero;  // a[nt][et]
    const unsigned short* W1b = &Wg1[(size_t)(layer * 64) * 136];
    #pragma unroll
    for (int ks = 0; ks < 4; ++ks) {
        short8 fa0 = *(const short8*)&W1b[(ch * 32 +      l15) * 136 + ks * 32 + g * 8];
        short8 fa1 = *(const short8*)&W1b[(ch * 32 + 16 + l15) * 136 + ks * 32 + g * 8];
        short8 fb0 = *(const short8*)&xls[(eh * 32 +      l15) * 136 + ks * 32 + g * 8];
        short8 fb1 = *(const short8*)&xls[(eh * 32 + 16 + l15) * 136 + ks * 32 + g * 8];
        a00 = __builtin_amdgcn_mfma_f32_16x16x32_bf16(fa0, fb0, a00, 0, 0, 0);
        a01 = __builtin_amdgcn_mfma_f32_16x16x32_bf16(fa0, fb1, a01, 0, 0, 0);
        a10 = __builtin_amdgcn_mfma_f32_16x16x32_bf16(fa1, fb0, a10, 0, 0, 0);
        a11 = __builtin_amdgcn_mfma_f32_16x16x32_bf16(fa1, fb1, a11, 0, 0, 0);
    }

    // ---- + d2 row (fp32) + bias, SiLU, quantize -> m1l ----
    {
        const float* Wr = &We1[((size_t)layer * 129 + 128) * 64];
        const float* B1 = &be1[layer * 64];
        float d2e0 = sD2[eh * 32 + l15];
        float d2e1 = sD2[eh * 32 + 16 + l15];
        #pragma unroll
        for (int nt = 0; nt < 2; ++nt) {
            int n0 = ch * 32 + nt * 16 + g * 4;
            float4 wr = *(const float4*)&Wr[n0];
            float4 bb = *(const float4*)&B1[n0];
            f32x4 acc0 = (nt == 0) ? a00 : a10;
            f32x4 acc1 = (nt == 0) ? a01 : a11;
            int e0 = eh * 32 + l15;
            int e1 = eh * 32 + 16 + l15;
            float r0 = silu_f(acc0.x + d2e0 * wr.x + bb.x);
            float r1 = silu_f(acc0.y + d2e0 * wr.y + bb.y);
            float r2 = silu_f(acc0.z + d2e0 * wr.z + bb.z);
            float r3 = silu_f(acc0.w + d2e0 * wr.w + bb.w);
            *(uint2*)&m1l[e0 * 72 + n0] = make_uint2(pk2(r0, r1), pk2(r2, r3));
            r0 = silu_f(acc1.x + d2e1 * wr.x + bb.x);
            r1 = silu_f(acc1.y + d2e1 * wr.y + bb.y);
            r2 = silu_f(acc1.z + d2e1 * wr.z + bb.z);
            r3 = silu_f(acc1.w + d2e1 * wr.w + bb.w);
            *(uint2*)&m1l[e1 * 72 + n0] = make_uint2(pk2(r0, r1), pk2(r2, r3));
        }
    }
    __syncthreads();

    // ---- GEMM2: D^T[n2][e] = sum_h W2[h][n2] * m1[e][h], K=64 ----
    f32x4 c00 = zero, c01 = zero, c10 = zero, c11 = zero;
    const unsigned short* W2b = &Wg2[(size_t)(layer * 64) * 72];
    #pragma unroll
    for (int ks = 0; ks < 2; ++ks) {
        short8 fa0 = *(const short8*)&W2b[(ch * 32 +      l15) * 72 + ks * 32 + g * 8];
        short8 fa1 = *(const short8*)&W2b[(ch * 32 + 16 + l15) * 72 + ks * 32 + g * 8];
        short8 fb0 = *(const short8*)&m1l[(eh * 32 +      l15) * 72 + ks * 32 + g * 8];
        short8 fb1 = *(const short8*)&m1l[(eh * 32 + 16 + l15) * 72 + ks * 32 + g * 8];
        c00 = __builtin_amdgcn_mfma_f32_16x16x32_bf16(fa0, fb0, c00, 0, 0, 0);
        c01 = __builtin_amdgcn_mfma_f32_16x16x32_bf16(fa0, fb1, c01, 0, 0, 0);
        c10 = __builtin_amdgcn_mfma_f32_16x16x32_bf16(fa1, fb0, c10, 0, 0, 0);
        c11 = __builtin_amdgcn_mfma_f32_16x16x32_bf16(fa1, fb1, c11, 0, 0, 0);
    }

    // ---- + bias, SiLU -> m2 (fp32 regs) ----
    float m2v[2][2][4];
    {
        const float* B2 = &be2[layer * 64];
        #pragma unroll
        for (int nt = 0; nt < 2; ++nt) {
            int n0 = ch * 32 + nt * 16 + g * 4;
            float4 bb = *(const float4*)&B2[n0];
            f32x4 acc0 = (nt == 0) ? c00 : c10;
            f32x4 acc1 = (nt == 0) ? c01 : c11;
            m2v[nt][0][0] = silu_f(acc0.x + bb.x);
            m2v[nt][0][1] = silu_f(acc0.y + bb.y);
            m2v[nt][0][2] = silu_f(acc0.z + bb.z);
            m2v[nt][0][3] = silu_f(acc0.w + bb.w);
            m2v[nt][1][0] = silu_f(acc1.x + bb.x);
            m2v[nt][1][1] = silu_f(acc1.y + bb.y);
            m2v[nt][1][2] = silu_f(acc1.z + bb.z);
            m2v[nt][1][3] = silu_f(acc1.w + bb.w);
        }
    }

    if (POS) {
        // stash m2 fp32 into xls region (dead after GEMM1; barrier above covers it)
        float* sM2f = (float*)xls;   // [64][65] floats = 16640 B <= 17408 B
        #pragma unroll
        for (int nt = 0; nt < 2; ++nt) {
            int n0 = ch * 32 + nt * 16 + g * 4;
            int e0 = eh * 32 + l15;
            int e1 = eh * 32 + 16 + l15;
            #pragma unroll
            for (int j = 0; j < 4; ++j) {
                sM2f[e0 * 65 + n0 + j] = m2v[nt][0][j];
                sM2f[e1 * 65 + n0 + j] = m2v[nt][1][j];
            }
        }
        __syncthreads();
        // pos head in fp32: lane = edge, wave covers 16 hidden channels
        const int wofs = __builtin_amdgcn_readfirstlane(w * 16);
        float p1[16];
        {
            const float* b = &bp1[(size_t)layer * 64 + wofs];
            #pragma unroll
            for (int hh = 0; hh < 16; ++hh) p1[hh] = b[hh];
        }
        const float* P1 = &Wp1[(size_t)layer * 64 * 64 + wofs];
        for (int k = 0; k < 64; ++k) {
            float mv = sM2f[lane * 65 + k];
            const float* wr = P1 + k * 64;
            #pragma unroll
            for (int hh = 0; hh < 16; ++hh) p1[hh] = fmaf(mv, wr[hh], p1[hh]);
        }
        float part = 0.0f;
        {
            const float* P2 = &Wp2[(size_t)layer * 64 + wofs];
            #pragma unroll
            for (int hh = 0; hh < 16; ++hh) part += silu_f(p1[hh]) * P2[hh];
        }
        atomicAdd(&sC[lane], part);
        __syncthreads();
        if (w == 0) {
            float c = sC[lane];
            int d = sDst[lane], s = sSrc[lane];
            float rx = pos[3*d+0] - pos[3*s+0];
            float ry = pos[3*d+1] - pos[3*s+1];
            float rz = pos[3*d+2] - pos[3*s+2];
            atomicAdd(&dpos[3*(size_t)d+0], rx * c);
            atomicAdd(&dpos[3*(size_t)d+1], ry * c);
            atomicAdd(&dpos[3*(size_t)d+2], rz * c);
        }
    }

    // ---- scatter m2 (fp32) into agg ----
    {
        int d0 = sDst[eh * 32 + l15];
        int d1 = sDst[eh * 32 + 16 + l15];
        #pragma unroll
        for (int nt = 0; nt < 2; ++nt) {
            int n0 = ch * 32 + nt * 16 + g * 4;
            #pragma unroll
            for (int j = 0; j < 4; ++j) {
                atomicAdd(&agg[(size_t)d0 * 64 + n0 + j], m2v[nt][0][j]);
                atomicAdd(&agg[(size_t)d1 * 64 + n0 + j], m2v[nt][1][j]);
            }
        }
    }
}

// ---------------- node MLP (fp32 VALU, tile of 64 nodes per block) ----------------
__global__ __launch_bounds__(256) void egnn_node(
    const float* __restrict__ x, const float* __restrict__ agg,
    const float* __restrict__ Wn1, const float* __restrict__ bn1,
    const float* __restrict__ Wn2, const float* __restrict__ bn2,
    float* __restrict__ xout, int layer)
{
    __shared__ float sX[64 * 65];
    __shared__ float sA[64 * 65];

    const int t    = threadIdx.x;
    const int w    = t >> 6;
    const int lane = t & 63;
    const int base = blockIdx.x * 64;
    const int nval = (NN - base < 64) ? (NN - base) : 64;
    const int wofs = __builtin_amdgcn_readfirstlane(w * 16);

    #pragma unroll
    for (int i = 0; i < 4; ++i) {
        int idx = i * 256 + t;
        int e = idx >> 4, c = idx & 15;
        if (e < nval) {
            const float4 vx = *reinterpret_cast<const float4*>(&x[(size_t)(base + e) * 64 + c * 4]);
            const float4 va = *reinterpret_cast<const float4*>(&agg[(size_t)(base + e) * 64 + c * 4]);
            float* px = &sX[e * 65 + c * 4];
            float* pa = &sA[e * 65 + c * 4];
            px[0]=vx.x; px[1]=vx.y; px[2]=vx.z; px[3]=vx.w;
            pa[0]=va.x; pa[1]=va.y; pa[2]=va.z; pa[3]=va.w;
        }
    }
    __syncthreads();

    float acc[16];
    {
        const float* b = &bn1[(size_t)layer * 64 + wofs];
        #pragma unroll
        for (int hh = 0; hh < 16; ++hh) acc[hh] = b[hh];
    }
    const float* W1 = &Wn1[(size_t)layer * 128 * 64 + wofs];
    for (int k = 0; k < 64; ++k) {
        float inv = sX[lane * 65 + k];
        const float* wr = W1 + k * 64;
        #pragma unroll
        for (int hh = 0; hh < 16; ++hh) acc[hh] = fmaf(inv, wr[hh], acc[hh]);
    }
    for (int k = 0; k < 64; ++k) {
        float inv = sA[lane * 65 + k];
        const float* wr = W1 + (64 + k) * 64;
        #pragma unroll
        for (int hh = 0; hh < 16; ++hh) acc[hh] = fmaf(inv, wr[hh], acc[hh]);
    }
    #pragma unroll
    for (int hh = 0; hh < 16; ++hh) acc[hh] = silu_f(acc[hh]);
    __syncthreads();
    #pragma unroll
    for (int hh = 0; hh < 16; ++hh) sA[lane * 65 + wofs + hh] = acc[hh];
    __syncthreads();

    float o[16];
    {
        const float* b = &bn2[(size_t)layer * 64 + wofs];
        #pragma unroll
        for (int hh = 0; hh < 16; ++hh) o[hh] = b[hh];
    }
    const float* W2 = &Wn2[(size_t)layer * 64 * 64 + wofs];
    for (int k = 0; k < 64; ++k) {
        float inv = sA[lane * 65 + k];
        const float* wr = W2 + k * 64;
        #pragma unroll
        for (int hh = 0; hh < 16; ++hh) o[hh] = fmaf(inv, wr[hh], o[hh]);
    }
    #pragma unroll
    for (int hh = 0; hh < 16; ++hh) sX[lane * 65 + wofs + hh] = o[hh];
    __syncthreads();
    #pragma unroll
    for (int i = 0; i < 4; ++i) {
        int idx = i * 256 + t;
        int e = idx >> 4, c = idx & 15;
        if (e < nval) {
            float4 v;
            const float* p = &sX[e * 65 + c * 4];
            v.x = p[0]; v.y = p[1]; v.z = p[2]; v.w = p[3];
            *reinterpret_cast<float4*>(&xout[(size_t)(base + e) * 64 + c * 4]) = v;
        }
    }
}

// ---------------- finalize positions ----------------
__global__ __launch_bounds__(256) void egnn_final(
    const float* __restrict__ pos, const float* __restrict__ dpos,
    const float* __restrict__ deg, const float* __restrict__ logit,
    float* __restrict__ pos_out)
{
    int i = blockIdx.x * 256 + threadIdx.x;
    if (i >= NN * 3) return;
    int node = i / 3;
    float dg = fmaxf(deg[node], 1.0f);
    float sig = 1.0f / (1.0f + __expf(-logit[0]));
    float upd = (dpos[i] / dg) * sig;
    upd = fminf(fmaxf(upd, -5.0f), 5.0f);
    float p = pos[i] + upd;
    pos_out[i] = fminf(fmaxf(p, -500.0f), 500.0f);
}

extern "C" void kernel_launch(void* const* d_in, const int* in_sizes, int n_in,
                              void* d_out, int out_size, void* d_ws, size_t ws_size,
                              hipStream_t stream)
{
    const float* x0    = (const float*)d_in[0];
    const float* pos   = (const float*)d_in[1];
    const int*   src   = (const int*)d_in[2];
    const int*   dst   = src + NE;
    const float* We1   = (const float*)d_in[3];
    const float* be1   = (const float*)d_in[4];
    const float* We2   = (const float*)d_in[5];
    const float* be2   = (const float*)d_in[6];
    const float* Wn1   = (const float*)d_in[7];
    const float* bn1   = (const float*)d_in[8];
    const float* Wn2   = (const float*)d_in[9];
    const float* bn2   = (const float*)d_in[10];
    const float* Wp1   = (const float*)d_in[11];
    const float* bp1   = (const float*)d_in[12];
    const float* Wp2   = (const float*)d_in[13];
    const float* bp2   = (const float*)d_in[14];
    const float* logit = (const float*)d_in[15];

    float* xout    = (float*)d_out;                 // [NN,64]
    float* pos_out = xout + (size_t)NN * 64;        // [NN,3]

    float* ws  = (float*)d_ws;
    float* xA  = ws;  ws += (size_t)NN * 64;        // 3.2M
    float* agg = ws;  ws += (size_t)NN * 64;        // 3.2M
    float* d2  = ws;  ws += NE;                     // 800k
    float* deg = ws;  ws += NN;                     // 50k
    float* dpos= ws;  ws += (size_t)NN * 3;         // 150k
    unsigned short* Wg1 = (unsigned short*)ws;      // 4*64*136 bf16
    unsigned short* Wg2 = Wg1 + 4 * 64 * 136;       // 4*64*72 bf16

    hipMemsetAsync(deg, 0, NN * sizeof(float), stream);
    hipMemsetAsync(dpos, 0, (size_t)NN * 3 * sizeof(float), stream);
    egnn_prep<<<NE / 256 + 1, 256, 0, stream>>>(src, dst, pos, d2, deg);
    egnn_prep_w<<<128, 256, 0, stream>>>(We1, We2, Wg1, Wg2);

    const float* xin = x0;
    for (int l = 0; l < 4; ++l) {
        hipMemsetAsync(agg, 0, (size_t)NN * 64 * sizeof(float), stream);
        if (l == 3) {
            egnn_edge<true><<<NE / 64, 256, 0, stream>>>(
                xin, d2, src, dst, pos, Wg1, Wg2, We1, be1, be2,
                Wp1, bp1, Wp2, bp2, agg, dpos, l);
        } else {
            egnn_edge<false><<<NE / 64, 256, 0, stream>>>(
                xin, d2, src, dst, pos, Wg1, Wg2, We1, be1, be2,
                Wp1, bp1, Wp2, bp2, agg, dpos, l);
        }
        float* xo = (l % 2 == 0) ? xA : xout;       // l0->xA, l1->xout, l2->xA, l3->xout
        egnn_node<<<(NN + 63) / 64, 256, 0, stream>>>(xin, agg, Wn1, bn1, Wn2, bn2, xo, l);
        xin = xo;
    }
    egnn_final<<<(NN * 3 + 255) / 256, 256, 0, stream>>>(pos, dpos, deg, logit, pos_out);
}

// Round 4
// 1159.455 us; speedup vs baseline: 2.6676x; 2.6676x over previous
//
#include <hip/hip_runtime.h>

#define NN 50000
#define NE 800000

typedef __attribute__((ext_vector_type(8))) short short8;
typedef __attribute__((ext_vector_type(4))) float f32x4;

__device__ __forceinline__ float silu_f(float v) {
    return v / (1.0f + __expf(-v));
}
__device__ __forceinline__ unsigned short f2bf(float f) {
    unsigned u = __float_as_uint(f);
    u += 0x7fffu + ((u >> 16) & 1u);        // round-to-nearest-even
    return (unsigned short)(u >> 16);
}
__device__ __forceinline__ unsigned pk2(float a, float b) {
    return (unsigned)f2bf(a) | ((unsigned)f2bf(b) << 16);
}

// ---------------- CSR build: histogram of dst ----------------
__global__ __launch_bounds__(256) void egnn_hist(
    const int* __restrict__ dst, int* __restrict__ hc)
{
    int e = blockIdx.x * 256 + threadIdx.x;
    if (e < NE) atomicAdd(&hc[dst[e]], 1);
}

// ---------------- CSR build: exclusive scan (1 block, 1024 thr) ----------------
// hc (hist) -> rowptr[0..NN]; hc becomes the scatter cursor (= rowptr copy).
__global__ __launch_bounds__(1024) void egnn_scan(
    int* __restrict__ hc, int* __restrict__ rowptr)
{
    __shared__ int part[1024];
    const int t = threadIdx.x;
    const int C = (NN + 1023) / 1024;   // 49
    const int b0 = t * C;
    int s = 0;
    for (int i = 0; i < C; ++i) {
        int idx = b0 + i;
        if (idx < NN) s += hc[idx];
    }
    part[t] = s;
    __syncthreads();
    for (int off = 1; off < 1024; off <<= 1) {
        int v = (t >= off) ? part[t - off] : 0;
        __syncthreads();
        part[t] += v;
        __syncthreads();
    }
    int run = part[t] - s;              // exclusive base for this chunk
    for (int i = 0; i < C; ++i) {
        int idx = b0 + i;
        if (idx < NN) {
            int v = hc[idx];
            rowptr[idx] = run;
            hc[idx] = run;              // cursor init
            run += v;
        }
    }
    if (t == 1023) rowptr[NN] = part[1023];
}

// ---------------- CSR build: permute edges into dst-sorted order ----------------
__global__ __launch_bounds__(256) void egnn_scatter(
    const int* __restrict__ src, const int* __restrict__ dst,
    const float* __restrict__ pos, int* __restrict__ cursor,
    int* __restrict__ eSrc, int* __restrict__ eDst, float* __restrict__ eD2)
{
    int e = blockIdx.x * 256 + threadIdx.x;
    if (e >= NE) return;
    int s = src[e], d = dst[e];
    float rx = pos[3*d+0] - pos[3*s+0];
    float ry = pos[3*d+1] - pos[3*s+1];
    float rz = pos[3*d+2] - pos[3*s+2];
    int p = atomicAdd(&cursor[d], 1);
    eSrc[p] = s;
    eDst[p] = d;
    eD2[p]  = rx*rx + ry*ry + rz*rz;
}

// ---------------- weight prep: transpose + bf16-convert edge weights ----------------
__global__ __launch_bounds__(256) void egnn_prep_w(
    const float* __restrict__ We1, const float* __restrict__ We2,
    unsigned short* __restrict__ Wg1, unsigned short* __restrict__ Wg2)
{
    int i = blockIdx.x * 256 + threadIdx.x;
    if (i < 4 * 64 * 128) {
        int k = i & 127, n = (i >> 7) & 63, l = i >> 13;
        Wg1[(size_t)(l * 64 + n) * 136 + k] = f2bf(We1[((size_t)l * 129 + k) * 64 + n]);
    }
    if (i < 4 * 64 * 64) {
        int h = i & 63, n = (i >> 6) & 63, l = i >> 12;
        Wg2[(size_t)(l * 64 + n) * 72 + h] = f2bf(We2[((size_t)l * 64 + h) * 64 + n]);
    }
}

// ---------------- edge MLP via bf16 MFMA + segmented-run scatter ----------------
// 64 sorted edges/block, 4 waves. Wave w: edge-half eh=w>>1, col-half ch=w&1.
template<bool POS>
__global__ __launch_bounds__(256) void egnn_edge(
    const float* __restrict__ x, const float* __restrict__ eD2,
    const int* __restrict__ eSrc, const int* __restrict__ eDst,
    const float* __restrict__ pos,
    const unsigned short* __restrict__ Wg1, const unsigned short* __restrict__ Wg2,
    const float* __restrict__ We1,   // fp32, d2 row (row 128)
    const float* __restrict__ be1, const float* __restrict__ be2,
    const float* __restrict__ Wp1, const float* __restrict__ bp1,
    const float* __restrict__ Wp2, const float* __restrict__ bp2,
    float* __restrict__ agg, float* __restrict__ dpos, int layer)
{
    __shared__ __align__(16) unsigned short xls[64 * 136];  // bf16 [e][k]; later fp32 m2 [64][65]
    __shared__ __align__(16) unsigned short m1l[64 * 72];   // bf16 [e][h]
    __shared__ int   sSrc[64];
    __shared__ int   sDst[64];
    __shared__ float sD2[64];
    __shared__ float sC[64];

    const int t    = threadIdx.x;
    const int lane = t & 63;
    const int w    = t >> 6;
    const int l15  = lane & 15;
    const int g    = lane >> 4;
    const int eh   = w >> 1;
    const int ch   = w & 1;
    const int base = blockIdx.x * 64;

    if (t < 64) {
        sSrc[t] = eSrc[base + t];
        sDst[t] = eDst[base + t];
        sD2[t]  = eD2[base + t];
        if (POS) sC[t] = bp2[layer];
    }
    __syncthreads();

    // ---- gather + bf16-convert x[dst] || x[src] into xls ----
    {
        int e = t >> 2, q = t & 3;
        const float4* pd = (const float4*)&x[(size_t)sDst[e] * 64 + q * 16];
        const float4* ps = (const float4*)&x[(size_t)sSrc[e] * 64 + q * 16];
        unsigned short* row = &xls[e * 136];
        #pragma unroll
        for (int i2 = 0; i2 < 4; ++i2) {
            float4 v = pd[i2];
            *(uint2*)&row[q * 16 + i2 * 4] = make_uint2(pk2(v.x, v.y), pk2(v.z, v.w));
        }
        #pragma unroll
        for (int i2 = 0; i2 < 4; ++i2) {
            float4 v = ps[i2];
            *(uint2*)&row[64 + q * 16 + i2 * 4] = make_uint2(pk2(v.x, v.y), pk2(v.z, v.w));
        }
    }
    __syncthreads();

    // ---- GEMM1: D^T[n][e] = sum_k W1[k][n] * cat[e][k], K=128 ----
    const f32x4 zero = {0.f, 0.f, 0.f, 0.f};
    f32x4 a00 = zero, a01 = zero, a10 = zero, a11 = zero;
    const unsigned short* W1b = &Wg1[(size_t)(layer * 64) * 136];
    #pragma unroll
    for (int ks = 0; ks < 4; ++ks) {
        short8 fa0 = *(const short8*)&W1b[(ch * 32 +      l15) * 136 + ks * 32 + g * 8];
        short8 fa1 = *(const short8*)&W1b[(ch * 32 + 16 + l15) * 136 + ks * 32 + g * 8];
        short8 fb0 = *(const short8*)&xls[(eh * 32 +      l15) * 136 + ks * 32 + g * 8];
        short8 fb1 = *(const short8*)&xls[(eh * 32 + 16 + l15) * 136 + ks * 32 + g * 8];
        a00 = __builtin_amdgcn_mfma_f32_16x16x32_bf16(fa0, fb0, a00, 0, 0, 0);
        a01 = __builtin_amdgcn_mfma_f32_16x16x32_bf16(fa0, fb1, a01, 0, 0, 0);
        a10 = __builtin_amdgcn_mfma_f32_16x16x32_bf16(fa1, fb0, a10, 0, 0, 0);
        a11 = __builtin_amdgcn_mfma_f32_16x16x32_bf16(fa1, fb1, a11, 0, 0, 0);
    }

    // ---- + d2 row (fp32) + bias, SiLU, quantize -> m1l ----
    {
        const float* Wr = &We1[((size_t)layer * 129 + 128) * 64];
        const float* B1 = &be1[layer * 64];
        float d2e0 = sD2[eh * 32 + l15];
        float d2e1 = sD2[eh * 32 + 16 + l15];
        #pragma unroll
        for (int nt = 0; nt < 2; ++nt) {
            int n0 = ch * 32 + nt * 16 + g * 4;
            float4 wr = *(const float4*)&Wr[n0];
            float4 bb = *(const float4*)&B1[n0];
            f32x4 acc0 = (nt == 0) ? a00 : a10;
            f32x4 acc1 = (nt == 0) ? a01 : a11;
            int e0 = eh * 32 + l15;
            int e1 = eh * 32 + 16 + l15;
            float r0 = silu_f(acc0.x + d2e0 * wr.x + bb.x);
            float r1 = silu_f(acc0.y + d2e0 * wr.y + bb.y);
            float r2 = silu_f(acc0.z + d2e0 * wr.z + bb.z);
            float r3 = silu_f(acc0.w + d2e0 * wr.w + bb.w);
            *(uint2*)&m1l[e0 * 72 + n0] = make_uint2(pk2(r0, r1), pk2(r2, r3));
            r0 = silu_f(acc1.x + d2e1 * wr.x + bb.x);
            r1 = silu_f(acc1.y + d2e1 * wr.y + bb.y);
            r2 = silu_f(acc1.z + d2e1 * wr.z + bb.z);
            r3 = silu_f(acc1.w + d2e1 * wr.w + bb.w);
            *(uint2*)&m1l[e1 * 72 + n0] = make_uint2(pk2(r0, r1), pk2(r2, r3));
        }
    }
    __syncthreads();

    // ---- GEMM2: D^T[n2][e] = sum_h W2[h][n2] * m1[e][h], K=64 ----
    f32x4 c00 = zero, c01 = zero, c10 = zero, c11 = zero;
    const unsigned short* W2b = &Wg2[(size_t)(layer * 64) * 72];
    #pragma unroll
    for (int ks = 0; ks < 2; ++ks) {
        short8 fa0 = *(const short8*)&W2b[(ch * 32 +      l15) * 72 + ks * 32 + g * 8];
        short8 fa1 = *(const short8*)&W2b[(ch * 32 + 16 + l15) * 72 + ks * 32 + g * 8];
        short8 fb0 = *(const short8*)&m1l[(eh * 32 +      l15) * 72 + ks * 32 + g * 8];
        short8 fb1 = *(const short8*)&m1l[(eh * 32 + 16 + l15) * 72 + ks * 32 + g * 8];
        c00 = __builtin_amdgcn_mfma_f32_16x16x32_bf16(fa0, fb0, c00, 0, 0, 0);
        c01 = __builtin_amdgcn_mfma_f32_16x16x32_bf16(fa0, fb1, c01, 0, 0, 0);
        c10 = __builtin_amdgcn_mfma_f32_16x16x32_bf16(fa1, fb0, c10, 0, 0, 0);
        c11 = __builtin_amdgcn_mfma_f32_16x16x32_bf16(fa1, fb1, c11, 0, 0, 0);
    }

    // ---- + bias, SiLU -> m2 fp32, stage to LDS [64][65] ----
    float* sM2f = (float*)xls;   // xls dead after GEMM1 (m1l barrier passed)
    {
        const float* B2 = &be2[layer * 64];
        #pragma unroll
        for (int nt = 0; nt < 2; ++nt) {
            int n0 = ch * 32 + nt * 16 + g * 4;
            float4 bb = *(const float4*)&B2[n0];
            f32x4 acc0 = (nt == 0) ? c00 : c10;
            f32x4 acc1 = (nt == 0) ? c01 : c11;
            int e0 = eh * 32 + l15;
            int e1 = eh * 32 + 16 + l15;
            sM2f[e0 * 65 + n0 + 0] = silu_f(acc0.x + bb.x);
            sM2f[e0 * 65 + n0 + 1] = silu_f(acc0.y + bb.y);
            sM2f[e0 * 65 + n0 + 2] = silu_f(acc0.z + bb.z);
            sM2f[e0 * 65 + n0 + 3] = silu_f(acc0.w + bb.w);
            sM2f[e1 * 65 + n0 + 0] = silu_f(acc1.x + bb.x);
            sM2f[e1 * 65 + n0 + 1] = silu_f(acc1.y + bb.y);
            sM2f[e1 * 65 + n0 + 2] = silu_f(acc1.z + bb.z);
            sM2f[e1 * 65 + n0 + 3] = silu_f(acc1.w + bb.w);
        }
    }
    __syncthreads();

    if (POS) {
        // pos head fp32: lane = edge, wave covers 16 hidden channels
        const int wofs = __builtin_amdgcn_readfirstlane(w * 16);
        float p1[16];
        {
            const float* b = &bp1[(size_t)layer * 64 + wofs];
            #pragma unroll
            for (int hh = 0; hh < 16; ++hh) p1[hh] = b[hh];
        }
        const float* P1 = &Wp1[(size_t)layer * 64 * 64 + wofs];
        for (int k = 0; k < 64; ++k) {
            float mv = sM2f[lane * 65 + k];
            const float* wr = P1 + k * 64;
            #pragma unroll
            for (int hh = 0; hh < 16; ++hh) p1[hh] = fmaf(mv, wr[hh], p1[hh]);
        }
        float part = 0.0f;
        {
            const float* P2 = &Wp2[(size_t)layer * 64 + wofs];
            #pragma unroll
            for (int hh = 0; hh < 16; ++hh) part += silu_f(p1[hh]) * P2[hh];
        }
        atomicAdd(&sC[lane], part);
        __syncthreads();
        if (w == 0) {
            // run-accumulate rel*c over sorted dst (lane<3: x/y/z component)
            float c = sC[lane];
            int d = sDst[lane], s = sSrc[lane];
            float rx = pos[3*d+0] - pos[3*s+0];
            float ry = pos[3*d+1] - pos[3*s+1];
            float rz = pos[3*d+2] - pos[3*s+2];
            atomicAdd(&dpos[3*(size_t)d+0], rx * c);
            atomicAdd(&dpos[3*(size_t)d+1], ry * c);
            atomicAdd(&dpos[3*(size_t)d+2], rz * c);
        }
    }

    // ---- segmented-run scatter: wave w owns edges [w*16, w*16+16), lane = channel ----
    {
        int e0 = w * 16;
        float run = 0.0f;
        int cur = sDst[e0];
        #pragma unroll 1
        for (int i = 0; i < 16; ++i) {
            int e = e0 + i;
            int d = sDst[e];
            if (d != cur) {
                atomicAdd(&agg[(size_t)cur * 64 + lane], run);
                run = 0.0f;
                cur = d;
            }
            run += sM2f[e * 65 + lane];
        }
        atomicAdd(&agg[(size_t)cur * 64 + lane], run);
    }
}

// ---------------- node MLP (fp32 VALU, tile of 64 nodes per block) ----------------
__global__ __launch_bounds__(256) void egnn_node(
    const float* __restrict__ x, const float* __restrict__ agg,
    const float* __restrict__ Wn1, const float* __restrict__ bn1,
    const float* __restrict__ Wn2, const float* __restrict__ bn2,
    float* __restrict__ xout, int layer)
{
    __shared__ float sX[64 * 65];
    __shared__ float sA[64 * 65];

    const int t    = threadIdx.x;
    const int w    = t >> 6;
    const int lane = t & 63;
    const int base = blockIdx.x * 64;
    const int nval = (NN - base < 64) ? (NN - base) : 64;
    const int wofs = __builtin_amdgcn_readfirstlane(w * 16);

    #pragma unroll
    for (int i = 0; i < 4; ++i) {
        int idx = i * 256 + t;
        int e = idx >> 4, c = idx & 15;
        if (e < nval) {
            const float4 vx = *reinterpret_cast<const float4*>(&x[(size_t)(base + e) * 64 + c * 4]);
            const float4 va = *reinterpret_cast<const float4*>(&agg[(size_t)(base + e) * 64 + c * 4]);
            float* px = &sX[e * 65 + c * 4];
            float* pa = &sA[e * 65 + c * 4];
            px[0]=vx.x; px[1]=vx.y; px[2]=vx.z; px[3]=vx.w;
            pa[0]=va.x; pa[1]=va.y; pa[2]=va.z; pa[3]=va.w;
        }
    }
    __syncthreads();

    float acc[16];
    {
        const float* b = &bn1[(size_t)layer * 64 + wofs];
        #pragma unroll
        for (int hh = 0; hh < 16; ++hh) acc[hh] = b[hh];
    }
    const float* W1 = &Wn1[(size_t)layer * 128 * 64 + wofs];
    for (int k = 0; k < 64; ++k) {
        float inv = sX[lane * 65 + k];
        const float* wr = W1 + k * 64;
        #pragma unroll
        for (int hh = 0; hh < 16; ++hh) acc[hh] = fmaf(inv, wr[hh], acc[hh]);
    }
    for (int k = 0; k < 64; ++k) {
        float inv = sA[lane * 65 + k];
        const float* wr = W1 + (64 + k) * 64;
        #pragma unroll
        for (int hh = 0; hh < 16; ++hh) acc[hh] = fmaf(inv, wr[hh], acc[hh]);
    }
    #pragma unroll
    for (int hh = 0; hh < 16; ++hh) acc[hh] = silu_f(acc[hh]);
    __syncthreads();
    #pragma unroll
    for (int hh = 0; hh < 16; ++hh) sA[lane * 65 + wofs + hh] = acc[hh];
    __syncthreads();

    float o[16];
    {
        const float* b = &bn2[(size_t)layer * 64 + wofs];
        #pragma unroll
        for (int hh = 0; hh < 16; ++hh) o[hh] = b[hh];
    }
    const float* W2 = &Wn2[(size_t)layer * 64 * 64 + wofs];
    for (int k = 0; k < 64; ++k) {
        float inv = sA[lane * 65 + k];
        const float* wr = W2 + k * 64;
        #pragma unroll
        for (int hh = 0; hh < 16; ++hh) o[hh] = fmaf(inv, wr[hh], o[hh]);
    }
    #pragma unroll
    for (int hh = 0; hh < 16; ++hh) sX[lane * 65 + wofs + hh] = o[hh];
    __syncthreads();
    #pragma unroll
    for (int i = 0; i < 4; ++i) {
        int idx = i * 256 + t;
        int e = idx >> 4, c = idx & 15;
        if (e < nval) {
            float4 v;
            const float* p = &sX[e * 65 + c * 4];
            v.x = p[0]; v.y = p[1]; v.z = p[2]; v.w = p[3];
            *reinterpret_cast<float4*>(&xout[(size_t)(base + e) * 64 + c * 4]) = v;
        }
    }
}

// ---------------- finalize positions ----------------
__global__ __launch_bounds__(256) void egnn_final(
    const float* __restrict__ pos, const float* __restrict__ dpos,
    const int* __restrict__ rowptr, const float* __restrict__ logit,
    float* __restrict__ pos_out)
{
    int i = blockIdx.x * 256 + threadIdx.x;
    if (i >= NN * 3) return;
    int node = i / 3;
    float dg = fmaxf((float)(rowptr[node + 1] - rowptr[node]), 1.0f);
    float sig = 1.0f / (1.0f + __expf(-logit[0]));
    float upd = (dpos[i] / dg) * sig;
    upd = fminf(fmaxf(upd, -5.0f), 5.0f);
    float p = pos[i] + upd;
    pos_out[i] = fminf(fmaxf(p, -500.0f), 500.0f);
}

extern "C" void kernel_launch(void* const* d_in, const int* in_sizes, int n_in,
                              void* d_out, int out_size, void* d_ws, size_t ws_size,
                              hipStream_t stream)
{
    const float* x0    = (const float*)d_in[0];
    const float* pos   = (const float*)d_in[1];
    const int*   src   = (const int*)d_in[2];
    const int*   dst   = src + NE;
    const float* We1   = (const float*)d_in[3];
    const float* be1   = (const float*)d_in[4];
    const float* We2   = (const float*)d_in[5];
    const float* be2   = (const float*)d_in[6];
    const float* Wn1   = (const float*)d_in[7];
    const float* bn1   = (const float*)d_in[8];
    const float* Wn2   = (const float*)d_in[9];
    const float* bn2   = (const float*)d_in[10];
    const float* Wp1   = (const float*)d_in[11];
    const float* bp1   = (const float*)d_in[12];
    const float* Wp2   = (const float*)d_in[13];
    const float* bp2   = (const float*)d_in[14];
    const float* logit = (const float*)d_in[15];

    float* xout    = (float*)d_out;                 // [NN,64]
    float* pos_out = xout + (size_t)NN * 64;        // [NN,3]

    float* ws  = (float*)d_ws;
    float* xA   = ws;  ws += (size_t)NN * 64;       // 3.2M f
    float* agg  = ws;  ws += (size_t)NN * 64;       // 3.2M f
    float* dpos = ws;  ws += (size_t)NN * 3;
    float* eD2  = ws;  ws += NE;
    int* rowptr = (int*)ws;  ws += NN + 1;
    int* hc     = (int*)ws;  ws += NN;              // hist -> cursor
    int* eSrc   = (int*)ws;  ws += NE;
    int* eDst   = (int*)ws;  ws += NE;
    unsigned short* Wg1 = (unsigned short*)ws;      // 4*64*136 bf16
    unsigned short* Wg2 = Wg1 + 4 * 64 * 136;       // 4*64*72 bf16

    hipMemsetAsync(hc, 0, NN * sizeof(int), stream);
    hipMemsetAsync(dpos, 0, (size_t)NN * 3 * sizeof(float), stream);
    egnn_hist<<<NE / 256, 256, 0, stream>>>(dst, hc);
    egnn_scan<<<1, 1024, 0, stream>>>(hc, rowptr);
    egnn_scatter<<<NE / 256, 256, 0, stream>>>(src, dst, pos, hc, eSrc, eDst, eD2);
    egnn_prep_w<<<128, 256, 0, stream>>>(We1, We2, Wg1, Wg2);

    const float* xin = x0;
    for (int l = 0; l < 4; ++l) {
        hipMemsetAsync(agg, 0, (size_t)NN * 64 * sizeof(float), stream);
        if (l == 3) {
            egnn_edge<true><<<NE / 64, 256, 0, stream>>>(
                xin, eD2, eSrc, eDst, pos, Wg1, Wg2, We1, be1, be2,
                Wp1, bp1, Wp2, bp2, agg, dpos, l);
        } else {
            egnn_edge<false><<<NE / 64, 256, 0, stream>>>(
                xin, eD2, eSrc, eDst, pos, Wg1, Wg2, We1, be1, be2,
                Wp1, bp1, Wp2, bp2, agg, dpos, l);
        }
        float* xo = (l % 2 == 0) ? xA : xout;       // l0->xA, l1->xout, l2->xA, l3->xout
        egnn_node<<<(NN + 63) / 64, 256, 0, stream>>>(xin, agg, Wn1, bn1, Wn2, bn2, xo, l);
        xin = xo;
    }
    egnn_final<<<(NN * 3 + 255) / 256, 256, 0, stream>>>(pos, dpos, rowptr, logit, pos_out);
}

// Round 5
// 1143.560 us; speedup vs baseline: 2.7047x; 1.0139x over previous
//
#include <hip/hip_runtime.h>

#define NN 50000
#define NE 800000

typedef __attribute__((ext_vector_type(8))) short short8;
typedef __attribute__((ext_vector_type(4))) float f32x4;

__device__ __forceinline__ float silu_f(float v) {
    return v / (1.0f + __expf(-v));
}
__device__ __forceinline__ unsigned short f2bf(float f) {
    unsigned u = __float_as_uint(f);
    u += 0x7fffu + ((u >> 16) & 1u);        // round-to-nearest-even
    return (unsigned short)(u >> 16);
}
__device__ __forceinline__ unsigned pk2(float a, float b) {
    return (unsigned)f2bf(a) | ((unsigned)f2bf(b) << 16);
}
__device__ __forceinline__ void gload_lds16(const unsigned short* g, unsigned short* l) {
    __builtin_amdgcn_global_load_lds(
        (const __attribute__((address_space(1))) unsigned int*)g,
        (__attribute__((address_space(3))) unsigned int*)l, 16, 0, 0);
}

// ---------------- CSR build: histogram of dst ----------------
__global__ __launch_bounds__(256) void egnn_hist(
    const int* __restrict__ dst, int* __restrict__ hc)
{
    int e = blockIdx.x * 256 + threadIdx.x;
    if (e < NE) atomicAdd(&hc[dst[e]], 1);
}

// ---------------- CSR build: exclusive scan (1 block, 1024 thr) ----------------
__global__ __launch_bounds__(1024) void egnn_scan(
    int* __restrict__ hc, int* __restrict__ rowptr)
{
    __shared__ int part[1024];
    const int t = threadIdx.x;
    const int C = (NN + 1023) / 1024;   // 49
    const int b0 = t * C;
    int s = 0;
    for (int i = 0; i < C; ++i) {
        int idx = b0 + i;
        if (idx < NN) s += hc[idx];
    }
    part[t] = s;
    __syncthreads();
    for (int off = 1; off < 1024; off <<= 1) {
        int v = (t >= off) ? part[t - off] : 0;
        __syncthreads();
        part[t] += v;
        __syncthreads();
    }
    int run = part[t] - s;              // exclusive base for this chunk
    for (int i = 0; i < C; ++i) {
        int idx = b0 + i;
        if (idx < NN) {
            int v = hc[idx];
            rowptr[idx] = run;
            hc[idx] = run;              // cursor init
            run += v;
        }
    }
    if (t == 1023) rowptr[NN] = part[1023];
}

// ---------------- CSR build: permute edges into dst-sorted order ----------------
__global__ __launch_bounds__(256) void egnn_scatter(
    const int* __restrict__ src, const int* __restrict__ dst,
    const float* __restrict__ pos, int* __restrict__ cursor,
    int* __restrict__ eSrc, int* __restrict__ eDst, float* __restrict__ eD2)
{
    int e = blockIdx.x * 256 + threadIdx.x;
    if (e >= NE) return;
    int s = src[e], d = dst[e];
    float rx = pos[3*d+0] - pos[3*s+0];
    float ry = pos[3*d+1] - pos[3*s+1];
    float rz = pos[3*d+2] - pos[3*s+2];
    int p = atomicAdd(&cursor[d], 1);
    eSrc[p] = s;
    eDst[p] = d;
    eD2[p]  = rx*rx + ry*ry + rz*rz;
}

// ---------------- weight prep: transpose + bf16-convert edge weights ----------------
__global__ __launch_bounds__(256) void egnn_prep_w(
    const float* __restrict__ We1, const float* __restrict__ We2,
    unsigned short* __restrict__ Wg1, unsigned short* __restrict__ Wg2)
{
    int i = blockIdx.x * 256 + threadIdx.x;
    if (i < 4 * 64 * 128) {
        int k = i & 127, n = (i >> 7) & 63, l = i >> 13;
        Wg1[(size_t)(l * 64 + n) * 136 + k] = f2bf(We1[((size_t)l * 129 + k) * 64 + n]);
    }
    if (i < 4 * 64 * 64) {
        int h = i & 63, n = (i >> 6) & 63, l = i >> 12;
        Wg2[(size_t)(l * 64 + n) * 72 + h] = f2bf(We2[((size_t)l * 64 + h) * 64 + n]);
    }
}

// ---------------- x0 -> bf16 ----------------
__global__ __launch_bounds__(256) void egnn_xbf(
    const float* __restrict__ x, unsigned short* __restrict__ xbf)
{
    int i = blockIdx.x * 256 + threadIdx.x;   // one float4 per thread
    if (i >= NN * 16) return;
    float4 v = ((const float4*)x)[i];
    ((uint2*)xbf)[i] = make_uint2(pk2(v.x, v.y), pk2(v.z, v.w));
}

// ---------------- edge MLP via bf16 MFMA + gload_lds gather + segmented scatter ----------
// 64 sorted edges/block, 4 waves. Wave w: edge-half eh=w>>1, col-half ch=w&1.
// xls[e][k] bf16 (k: 0-63 dst, 64-127 src), row stride 256B, chunk-swizzled:
//   LDS chunk p of row e holds logical chunk p ^ (e&7)  (chunk = 16B = 8 ch)
template<bool POS>
__global__ __launch_bounds__(256) void egnn_edge(
    const unsigned short* __restrict__ xbf, const float* __restrict__ eD2,
    const int* __restrict__ eSrc, const int* __restrict__ eDst,
    const float* __restrict__ pos,
    const unsigned short* __restrict__ Wg1, const unsigned short* __restrict__ Wg2,
    const float* __restrict__ We1,   // fp32, d2 row (row 128)
    const float* __restrict__ be1, const float* __restrict__ be2,
    const float* __restrict__ Wp1, const float* __restrict__ bp1,
    const float* __restrict__ Wp2, const float* __restrict__ bp2,
    float* __restrict__ agg, float* __restrict__ dpos, int layer)
{
    // pool: phase A = xls[64*128]u16 (16KB) + m1l[64*72]u16 (9.2KB); phase B = sM2f[64*65]f32
    __shared__ __align__(16) unsigned char pool[64 * 128 * 2 + 64 * 72 * 2];
    unsigned short* xls  = (unsigned short*)pool;
    unsigned short* m1l  = (unsigned short*)(pool + 64 * 128 * 2);
    float*          sM2f = (float*)pool;
    __shared__ int   sSrc[64];
    __shared__ int   sDst[64];
    __shared__ float sD2[64];
    __shared__ float sC[64];

    const int t    = threadIdx.x;
    const int lane = t & 63;
    const int w    = t >> 6;
    const int l15  = lane & 15;
    const int g    = lane >> 4;
    const int eh   = w >> 1;
    const int ch   = w & 1;
    const int base = blockIdx.x * 64;

    if (t < 64) {
        sSrc[t] = eSrc[base + t];
        sDst[t] = eDst[base + t];
        sD2[t]  = eD2[base + t];
        if (POS) sC[t] = bp2[layer];
    }
    __syncthreads();

    // ---- gather bf16 rows direct to LDS (source-swizzled, linear dest) ----
    {
        const int er   = lane >> 4;          // row within 4-row group
        const int half = (lane >> 3) & 1;    // 0: dst-half, 1: src-half
        const int c    = lane & 7;           // 16B chunk within half
        #pragma unroll
        for (int i = 0; i < 4; ++i) {
            int e = w * 16 + i * 4 + er;
            int node = half ? sSrc[e] : sDst[e];
            const unsigned short* gsrc = &xbf[(size_t)node * 64 + ((c ^ (e & 7)) << 3)];
            gload_lds16(gsrc, &xls[w * 2048 + i * 512]);
        }
    }
    __syncthreads();   // compiler drains vmcnt before barrier

    // ---- GEMM1: D^T[n][e] = sum_k W1[k][n] * cat[e][k], K=128 ----
    const f32x4 zero = {0.f, 0.f, 0.f, 0.f};
    f32x4 a00 = zero, a01 = zero, a10 = zero, a11 = zero;
    const unsigned short* W1b = &Wg1[(size_t)(layer * 64) * 136];
    {
        const int r0 = (eh * 32 + l15) * 128;
        const int r1 = r0 + 16 * 128;
        const int r7 = l15 & 7;
        #pragma unroll
        for (int ks = 0; ks < 4; ++ks) {
            int col = (((ks << 2) + g) ^ r7) << 3;
            short8 fa0 = *(const short8*)&W1b[(ch * 32 +      l15) * 136 + ks * 32 + g * 8];
            short8 fa1 = *(const short8*)&W1b[(ch * 32 + 16 + l15) * 136 + ks * 32 + g * 8];
            short8 fb0 = *(const short8*)&xls[r0 + col];
            short8 fb1 = *(const short8*)&xls[r1 + col];
            a00 = __builtin_amdgcn_mfma_f32_16x16x32_bf16(fa0, fb0, a00, 0, 0, 0);
            a01 = __builtin_amdgcn_mfma_f32_16x16x32_bf16(fa0, fb1, a01, 0, 0, 0);
            a10 = __builtin_amdgcn_mfma_f32_16x16x32_bf16(fa1, fb0, a10, 0, 0, 0);
            a11 = __builtin_amdgcn_mfma_f32_16x16x32_bf16(fa1, fb1, a11, 0, 0, 0);
        }
    }

    // ---- + d2 row (fp32) + bias, SiLU, quantize -> m1l ----
    {
        const float* Wr = &We1[((size_t)layer * 129 + 128) * 64];
        const float* B1 = &be1[layer * 64];
        float d2e0 = sD2[eh * 32 + l15];
        float d2e1 = sD2[eh * 32 + 16 + l15];
        #pragma unroll
        for (int nt = 0; nt < 2; ++nt) {
            int n0 = ch * 32 + nt * 16 + g * 4;
            float4 wr = *(const float4*)&Wr[n0];
            float4 bb = *(const float4*)&B1[n0];
            f32x4 acc0 = (nt == 0) ? a00 : a10;
            f32x4 acc1 = (nt == 0) ? a01 : a11;
            int e0 = eh * 32 + l15;
            int e1 = eh * 32 + 16 + l15;
            float r0 = silu_f(acc0.x + d2e0 * wr.x + bb.x);
            float r1 = silu_f(acc0.y + d2e0 * wr.y + bb.y);
            float r2 = silu_f(acc0.z + d2e0 * wr.z + bb.z);
            float r3 = silu_f(acc0.w + d2e0 * wr.w + bb.w);
            *(uint2*)&m1l[e0 * 72 + n0] = make_uint2(pk2(r0, r1), pk2(r2, r3));
            r0 = silu_f(acc1.x + d2e1 * wr.x + bb.x);
            r1 = silu_f(acc1.y + d2e1 * wr.y + bb.y);
            r2 = silu_f(acc1.z + d2e1 * wr.z + bb.z);
            r3 = silu_f(acc1.w + d2e1 * wr.w + bb.w);
            *(uint2*)&m1l[e1 * 72 + n0] = make_uint2(pk2(r0, r1), pk2(r2, r3));
        }
    }
    __syncthreads();

    // ---- GEMM2: D^T[n2][e] = sum_h W2[h][n2] * m1[e][h], K=64 ----
    f32x4 c00 = zero, c01 = zero, c10 = zero, c11 = zero;
    const unsigned short* W2b = &Wg2[(size_t)(layer * 64) * 72];
    #pragma unroll
    for (int ks = 0; ks < 2; ++ks) {
        short8 fa0 = *(const short8*)&W2b[(ch * 32 +      l15) * 72 + ks * 32 + g * 8];
        short8 fa1 = *(const short8*)&W2b[(ch * 32 + 16 + l15) * 72 + ks * 32 + g * 8];
        short8 fb0 = *(const short8*)&m1l[(eh * 32 +      l15) * 72 + ks * 32 + g * 8];
        short8 fb1 = *(const short8*)&m1l[(eh * 32 + 16 + l15) * 72 + ks * 32 + g * 8];
        c00 = __builtin_amdgcn_mfma_f32_16x16x32_bf16(fa0, fb0, c00, 0, 0, 0);
        c01 = __builtin_amdgcn_mfma_f32_16x16x32_bf16(fa0, fb1, c01, 0, 0, 0);
        c10 = __builtin_amdgcn_mfma_f32_16x16x32_bf16(fa1, fb0, c10, 0, 0, 0);
        c11 = __builtin_amdgcn_mfma_f32_16x16x32_bf16(fa1, fb1, c11, 0, 0, 0);
    }
    __syncthreads();   // all waves done reading m1l (sM2f overlays it)

    // ---- + bias, SiLU -> m2 fp32, stage to LDS [64][65] ----
    {
        const float* B2 = &be2[layer * 64];
        #pragma unroll
        for (int nt = 0; nt < 2; ++nt) {
            int n0 = ch * 32 + nt * 16 + g * 4;
            float4 bb = *(const float4*)&B2[n0];
            f32x4 acc0 = (nt == 0) ? c00 : c10;
            f32x4 acc1 = (nt == 0) ? c01 : c11;
            int e0 = eh * 32 + l15;
            int e1 = eh * 32 + 16 + l15;
            sM2f[e0 * 65 + n0 + 0] = silu_f(acc0.x + bb.x);
            sM2f[e0 * 65 + n0 + 1] = silu_f(acc0.y + bb.y);
            sM2f[e0 * 65 + n0 + 2] = silu_f(acc0.z + bb.z);
            sM2f[e0 * 65 + n0 + 3] = silu_f(acc0.w + bb.w);
            sM2f[e1 * 65 + n0 + 0] = silu_f(acc1.x + bb.x);
            sM2f[e1 * 65 + n0 + 1] = silu_f(acc1.y + bb.y);
            sM2f[e1 * 65 + n0 + 2] = silu_f(acc1.z + bb.z);
            sM2f[e1 * 65 + n0 + 3] = silu_f(acc1.w + bb.w);
        }
    }
    __syncthreads();

    if (POS) {
        // pos head fp32: lane = edge, wave covers 16 hidden channels
        const int wofs = __builtin_amdgcn_readfirstlane(w * 16);
        float p1[16];
        {
            const float* b = &bp1[(size_t)layer * 64 + wofs];
            #pragma unroll
            for (int hh = 0; hh < 16; ++hh) p1[hh] = b[hh];
        }
        const float* P1 = &Wp1[(size_t)layer * 64 * 64 + wofs];
        for (int k = 0; k < 64; ++k) {
            float mv = sM2f[lane * 65 + k];
            const float* wr = P1 + k * 64;
            #pragma unroll
            for (int hh = 0; hh < 16; ++hh) p1[hh] = fmaf(mv, wr[hh], p1[hh]);
        }
        float part = 0.0f;
        {
            const float* P2 = &Wp2[(size_t)layer * 64 + wofs];
            #pragma unroll
            for (int hh = 0; hh < 16; ++hh) part += silu_f(p1[hh]) * P2[hh];
        }
        atomicAdd(&sC[lane], part);
        __syncthreads();
        if (w == 0) {
            float c = sC[lane];
            int d = sDst[lane], s = sSrc[lane];
            float rx = pos[3*d+0] - pos[3*s+0];
            float ry = pos[3*d+1] - pos[3*s+1];
            float rz = pos[3*d+2] - pos[3*s+2];
            atomicAdd(&dpos[3*(size_t)d+0], rx * c);
            atomicAdd(&dpos[3*(size_t)d+1], ry * c);
            atomicAdd(&dpos[3*(size_t)d+2], rz * c);
        }
    }

    // ---- segmented-run scatter: wave w owns edges [w*16, w*16+16), lane = channel ----
    {
        int e0 = w * 16;
        float run = 0.0f;
        int cur = sDst[e0];
        #pragma unroll 1
        for (int i = 0; i < 16; ++i) {
            int e = e0 + i;
            int d = sDst[e];
            if (d != cur) {
                atomicAdd(&agg[(size_t)cur * 64 + lane], run);
                run = 0.0f;
                cur = d;
            }
            run += sM2f[e * 65 + lane];
        }
        atomicAdd(&agg[(size_t)cur * 64 + lane], run);
    }
}

// ---------------- node MLP (fp32 VALU) + bf16 x export ----------------
__global__ __launch_bounds__(256) void egnn_node(
    const float* __restrict__ x, const float* __restrict__ agg,
    const float* __restrict__ Wn1, const float* __restrict__ bn1,
    const float* __restrict__ Wn2, const float* __restrict__ bn2,
    float* __restrict__ xout, unsigned short* __restrict__ xbf_out, int layer)
{
    __shared__ float sX[64 * 65];
    __shared__ float sA[64 * 65];

    const int t    = threadIdx.x;
    const int w    = t >> 6;
    const int lane = t & 63;
    const int base = blockIdx.x * 64;
    const int nval = (NN - base < 64) ? (NN - base) : 64;
    const int wofs = __builtin_amdgcn_readfirstlane(w * 16);

    #pragma unroll
    for (int i = 0; i < 4; ++i) {
        int idx = i * 256 + t;
        int e = idx >> 4, c = idx & 15;
        if (e < nval) {
            const float4 vx = *reinterpret_cast<const float4*>(&x[(size_t)(base + e) * 64 + c * 4]);
            const float4 va = *reinterpret_cast<const float4*>(&agg[(size_t)(base + e) * 64 + c * 4]);
            float* px = &sX[e * 65 + c * 4];
            float* pa = &sA[e * 65 + c * 4];
            px[0]=vx.x; px[1]=vx.y; px[2]=vx.z; px[3]=vx.w;
            pa[0]=va.x; pa[1]=va.y; pa[2]=va.z; pa[3]=va.w;
        }
    }
    __syncthreads();

    float acc[16];
    {
        const float* b = &bn1[(size_t)layer * 64 + wofs];
        #pragma unroll
        for (int hh = 0; hh < 16; ++hh) acc[hh] = b[hh];
    }
    const float* W1 = &Wn1[(size_t)layer * 128 * 64 + wofs];
    for (int k = 0; k < 64; ++k) {
        float inv = sX[lane * 65 + k];
        const float* wr = W1 + k * 64;
        #pragma unroll
        for (int hh = 0; hh < 16; ++hh) acc[hh] = fmaf(inv, wr[hh], acc[hh]);
    }
    for (int k = 0; k < 64; ++k) {
        float inv = sA[lane * 65 + k];
        const float* wr = W1 + (64 + k) * 64;
        #pragma unroll
        for (int hh = 0; hh < 16; ++hh) acc[hh] = fmaf(inv, wr[hh], acc[hh]);
    }
    #pragma unroll
    for (int hh = 0; hh < 16; ++hh) acc[hh] = silu_f(acc[hh]);
    __syncthreads();
    #pragma unroll
    for (int hh = 0; hh < 16; ++hh) sA[lane * 65 + wofs + hh] = acc[hh];
    __syncthreads();

    float o[16];
    {
        const float* b = &bn2[(size_t)layer * 64 + wofs];
        #pragma unroll
        for (int hh = 0; hh < 16; ++hh) o[hh] = b[hh];
    }
    const float* W2 = &Wn2[(size_t)layer * 64 * 64 + wofs];
    for (int k = 0; k < 64; ++k) {
        float inv = sA[lane * 65 + k];
        const float* wr = W2 + k * 64;
        #pragma unroll
        for (int hh = 0; hh < 16; ++hh) o[hh] = fmaf(inv, wr[hh], o[hh]);
    }
    // bf16 export for next layer's edge gather (from regs, coalesced 16B)
    if (lane < nval) {
        uint4 u0, u1;
        u0.x = pk2(o[0], o[1]);  u0.y = pk2(o[2],  o[3]);
        u0.z = pk2(o[4], o[5]);  u0.w = pk2(o[6],  o[7]);
        u1.x = pk2(o[8], o[9]);  u1.y = pk2(o[10], o[11]);
        u1.z = pk2(o[12], o[13]); u1.w = pk2(o[14], o[15]);
        *(uint4*)&xbf_out[(size_t)(base + lane) * 64 + wofs + 0] = u0;
        *(uint4*)&xbf_out[(size_t)(base + lane) * 64 + wofs + 8] = u1;
    }
    #pragma unroll
    for (int hh = 0; hh < 16; ++hh) sX[lane * 65 + wofs + hh] = o[hh];
    __syncthreads();
    #pragma unroll
    for (int i = 0; i < 4; ++i) {
        int idx = i * 256 + t;
        int e = idx >> 4, c = idx & 15;
        if (e < nval) {
            float4 v;
            const float* p = &sX[e * 65 + c * 4];
            v.x = p[0]; v.y = p[1]; v.z = p[2]; v.w = p[3];
            *reinterpret_cast<float4*>(&xout[(size_t)(base + e) * 64 + c * 4]) = v;
        }
    }
}

// ---------------- finalize positions ----------------
__global__ __launch_bounds__(256) void egnn_final(
    const float* __restrict__ pos, const float* __restrict__ dpos,
    const int* __restrict__ rowptr, const float* __restrict__ logit,
    float* __restrict__ pos_out)
{
    int i = blockIdx.x * 256 + threadIdx.x;
    if (i >= NN * 3) return;
    int node = i / 3;
    float dg = fmaxf((float)(rowptr[node + 1] - rowptr[node]), 1.0f);
    float sig = 1.0f / (1.0f + __expf(-logit[0]));
    float upd = (dpos[i] / dg) * sig;
    upd = fminf(fmaxf(upd, -5.0f), 5.0f);
    float p = pos[i] + upd;
    pos_out[i] = fminf(fmaxf(p, -500.0f), 500.0f);
}

extern "C" void kernel_launch(void* const* d_in, const int* in_sizes, int n_in,
                              void* d_out, int out_size, void* d_ws, size_t ws_size,
                              hipStream_t stream)
{
    const float* x0    = (const float*)d_in[0];
    const float* pos   = (const float*)d_in[1];
    const int*   src   = (const int*)d_in[2];
    const int*   dst   = src + NE;
    const float* We1   = (const float*)d_in[3];
    const float* be1   = (const float*)d_in[4];
    const float* We2   = (const float*)d_in[5];
    const float* be2   = (const float*)d_in[6];
    const float* Wn1   = (const float*)d_in[7];
    const float* bn1   = (const float*)d_in[8];
    const float* Wn2   = (const float*)d_in[9];
    const float* bn2   = (const float*)d_in[10];
    const float* Wp1   = (const float*)d_in[11];
    const float* bp1   = (const float*)d_in[12];
    const float* Wp2   = (const float*)d_in[13];
    const float* bp2   = (const float*)d_in[14];
    const float* logit = (const float*)d_in[15];

    float* xout    = (float*)d_out;                 // [NN,64]
    float* pos_out = xout + (size_t)NN * 64;        // [NN,3]

    float* ws  = (float*)d_ws;
    float* xA   = ws;  ws += (size_t)NN * 64;       // fp32 x ping
    float* agg  = ws;  ws += (size_t)NN * 64;
    float* dpos = ws;  ws += (size_t)NN * 3;
    float* eD2  = ws;  ws += NE;
    int* rowptr = (int*)ws;  ws += NN + 1;
    int* hc     = (int*)ws;  ws += NN;              // hist -> cursor
    int* eSrc   = (int*)ws;  ws += NE;
    int* eDst   = (int*)ws;  ws += NE;
    unsigned short* xbf = (unsigned short*)ws;      // [NN,64] bf16
    ws += (size_t)NN * 32;                          // NN*64 ushorts = NN*32 floats
    unsigned short* Wg1 = (unsigned short*)ws;      // 4*64*136 bf16
    unsigned short* Wg2 = Wg1 + 4 * 64 * 136;       // 4*64*72 bf16

    hipMemsetAsync(hc, 0, NN * sizeof(int), stream);
    hipMemsetAsync(dpos, 0, (size_t)NN * 3 * sizeof(float), stream);
    egnn_hist<<<NE / 256, 256, 0, stream>>>(dst, hc);
    egnn_scan<<<1, 1024, 0, stream>>>(hc, rowptr);
    egnn_scatter<<<NE / 256, 256, 0, stream>>>(src, dst, pos, hc, eSrc, eDst, eD2);
    egnn_prep_w<<<128, 256, 0, stream>>>(We1, We2, Wg1, Wg2);
    egnn_xbf<<<(NN * 16 + 255) / 256, 256, 0, stream>>>(x0, xbf);

    const float* xin = x0;
    for (int l = 0; l < 4; ++l) {
        hipMemsetAsync(agg, 0, (size_t)NN * 64 * sizeof(float), stream);
        if (l == 3) {
            egnn_edge<true><<<NE / 64, 256, 0, stream>>>(
                xbf, eD2, eSrc, eDst, pos, Wg1, Wg2, We1, be1, be2,
                Wp1, bp1, Wp2, bp2, agg, dpos, l);
        } else {
            egnn_edge<false><<<NE / 64, 256, 0, stream>>>(
                xbf, eD2, eSrc, eDst, pos, Wg1, Wg2, We1, be1, be2,
                Wp1, bp1, Wp2, bp2, agg, dpos, l);
        }
        float* xo = (l % 2 == 0) ? xA : xout;       // l0->xA, l1->xout, l2->xA, l3->xout
        egnn_node<<<(NN + 63) / 64, 256, 0, stream>>>(xin, agg, Wn1, bn1, Wn2, bn2, xo, xbf, l);
        xin = xo;
    }
    egnn_final<<<(NN * 3 + 255) / 256, 256, 0, stream>>>(pos, dpos, rowptr, logit, pos_out);
}

// Round 7
// 967.026 us; speedup vs baseline: 3.1984x; 1.1826x over previous
//
#include <hip/hip_runtime.h>

#define NN 50000
#define NE 800000
#define TPB 10   // tiles (of 64 edges) per block; 12500 % 10 == 0

typedef __attribute__((ext_vector_type(8))) short short8;
typedef __attribute__((ext_vector_type(4))) float f32x4;

__device__ __forceinline__ float silu_f(float v) {
    return v / (1.0f + __expf(-v));
}
__device__ __forceinline__ unsigned short f2bf(float f) {
    unsigned u = __float_as_uint(f);
    u += 0x7fffu + ((u >> 16) & 1u);        // round-to-nearest-even
    return (unsigned short)(u >> 16);
}
__device__ __forceinline__ unsigned pk2(float a, float b) {
    return (unsigned)f2bf(a) | ((unsigned)f2bf(b) << 16);
}
__device__ __forceinline__ void gload_lds16(const unsigned short* g, unsigned short* l) {
    __builtin_amdgcn_global_load_lds(
        (const __attribute__((address_space(1))) unsigned int*)g,
        (__attribute__((address_space(3))) unsigned int*)l, 16, 0, 0);
}
// lgkm-only barrier: drain LDS ops, leave vmcnt (in-flight gathers) alone
#define FENCE_BAR() do { \
    asm volatile("s_waitcnt lgkmcnt(0)" ::: "memory"); \
    __builtin_amdgcn_sched_barrier(0); \
    __builtin_amdgcn_s_barrier(); \
    __builtin_amdgcn_sched_barrier(0); \
} while (0)
// explicit full vmem drain (gathers landed); scheduler fence both sides
#define VMDRAIN() do { \
    __builtin_amdgcn_sched_barrier(0); \
    asm volatile("s_waitcnt vmcnt(0)" ::: "memory"); \
    __builtin_amdgcn_sched_barrier(0); \
} while (0)

// ---------------- CSR build: histogram of dst ----------------
__global__ __launch_bounds__(256) void egnn_hist(
    const int* __restrict__ dst, int* __restrict__ hc)
{
    int e = blockIdx.x * 256 + threadIdx.x;
    if (e < NE) atomicAdd(&hc[dst[e]], 1);
}

// ---------------- CSR build: exclusive scan (1 block, 1024 thr) ----------------
__global__ __launch_bounds__(1024) void egnn_scan(
    int* __restrict__ hc, int* __restrict__ rowptr)
{
    __shared__ int part[1024];
    const int t = threadIdx.x;
    const int C = (NN + 1023) / 1024;   // 49
    const int b0 = t * C;
    int s = 0;
    for (int i = 0; i < C; ++i) {
        int idx = b0 + i;
        if (idx < NN) s += hc[idx];
    }
    part[t] = s;
    __syncthreads();
    for (int off = 1; off < 1024; off <<= 1) {
        int v = (t >= off) ? part[t - off] : 0;
        __syncthreads();
        part[t] += v;
        __syncthreads();
    }
    int run = part[t] - s;              // exclusive base for this chunk
    for (int i = 0; i < C; ++i) {
        int idx = b0 + i;
        if (idx < NN) {
            int v = hc[idx];
            rowptr[idx] = run;
            hc[idx] = run;              // cursor init
            run += v;
        }
    }
    if (t == 1023) rowptr[NN] = part[1023];
}

// ---------------- CSR build: permute edges into dst-sorted order ----------------
__global__ __launch_bounds__(256) void egnn_scatter(
    const int* __restrict__ src, const int* __restrict__ dst,
    const float* __restrict__ pos, int* __restrict__ cursor,
    int* __restrict__ eSrc, int* __restrict__ eDst, float* __restrict__ eD2)
{
    int e = blockIdx.x * 256 + threadIdx.x;
    if (e >= NE) return;
    int s = src[e], d = dst[e];
    float rx = pos[3*d+0] - pos[3*s+0];
    float ry = pos[3*d+1] - pos[3*s+1];
    float rz = pos[3*d+2] - pos[3*s+2];
    int p = atomicAdd(&cursor[d], 1);
    eSrc[p] = s;
    eDst[p] = d;
    eD2[p]  = rx*rx + ry*ry + rz*rz;
}

// ---------------- weight prep: transpose + bf16-convert edge weights ----------------
__global__ __launch_bounds__(256) void egnn_prep_w(
    const float* __restrict__ We1, const float* __restrict__ We2,
    unsigned short* __restrict__ Wg1, unsigned short* __restrict__ Wg2)
{
    int i = blockIdx.x * 256 + threadIdx.x;
    if (i < 4 * 64 * 128) {
        int k = i & 127, n = (i >> 7) & 63, l = i >> 13;
        Wg1[(size_t)(l * 64 + n) * 136 + k] = f2bf(We1[((size_t)l * 129 + k) * 64 + n]);
    }
    if (i < 4 * 64 * 64) {
        int h = i & 63, n = (i >> 6) & 63, l = i >> 12;
        Wg2[(size_t)(l * 64 + n) * 72 + h] = f2bf(We2[((size_t)l * 64 + h) * 64 + n]);
    }
}

// ---------------- x0 -> bf16 ----------------
__global__ __launch_bounds__(256) void egnn_xbf(
    const float* __restrict__ x, unsigned short* __restrict__ xbf)
{
    int i = blockIdx.x * 256 + threadIdx.x;   // one float4 per thread
    if (i >= NN * 16) return;
    float4 v = ((const float4*)x)[i];
    ((uint2*)xbf)[i] = make_uint2(pk2(v.x, v.y), pk2(v.z, v.w));
}

// ---------------- edge MLP: multi-tile pipelined, bf16 MFMA ----------------
// TPB tiles of 64 edges per block. 4 waves: eh=w>>1 (32-edge half), ch=w&1 (32-ch half).
// Double-buffered xls; gather(t+1) issued at top of iter t, drained by the explicit
// per-iteration VMDRAIN before the scatter (T3-minimal counted-wait pattern).
template<bool POS>
__global__ __launch_bounds__(256) void egnn_edge(
    const unsigned short* __restrict__ xbf, const float* __restrict__ eD2,
    const int* __restrict__ eSrc, const int* __restrict__ eDst,
    const float* __restrict__ pos,
    const unsigned short* __restrict__ Wg1, const unsigned short* __restrict__ Wg2,
    const float* __restrict__ We1,   // fp32, d2 row (row 128)
    const float* __restrict__ be1, const float* __restrict__ be2,
    const float* __restrict__ Wp1, const float* __restrict__ bp1,
    const float* __restrict__ Wp2, const float* __restrict__ bp2,
    float* __restrict__ agg, float* __restrict__ dpos, int layer)
{
    // [xls0 16384][xls1 16384][m1l 9216 / sM2f 16640 overlay]
    __shared__ __align__(16) unsigned char pool[16384 * 2 + 16640];
    __shared__ int   sS[2][64];
    __shared__ int   sD[2][64];
    __shared__ float s2[2][64];
    __shared__ float sC[64];

    unsigned short* const xls0 = (unsigned short*)pool;
    unsigned short* const xls1 = (unsigned short*)(pool + 16384);
    unsigned short* const m1l  = (unsigned short*)(pool + 32768);
    float* const          sM2f = (float*)(pool + 32768);

    const int t    = threadIdx.x;
    const int lane = t & 63;
    const int w    = t >> 6;
    const int l15  = lane & 15;
    const int g    = lane >> 4;
    const int eh   = w >> 1;
    const int ch   = w & 1;
    const int er   = lane >> 4;          // gather: row within 4-row group
    const int half = (lane >> 3) & 1;    // gather: 0=dst-half, 1=src-half
    const int c    = lane & 7;           // gather: 16B chunk within half
    const int tile0 = blockIdx.x * TPB;

    // ---- hoist loop-invariant weight fragments ----
    const unsigned short* W1b = &Wg1[(size_t)(layer * 64) * 136];
    const unsigned short* W2b = &Wg2[(size_t)(layer * 64) * 72];
    short8 w1f0[4], w1f1[4], w2f0[2], w2f1[2];
    #pragma unroll
    for (int ks = 0; ks < 4; ++ks) {
        w1f0[ks] = *(const short8*)&W1b[(ch * 32 +      l15) * 136 + ks * 32 + g * 8];
        w1f1[ks] = *(const short8*)&W1b[(ch * 32 + 16 + l15) * 136 + ks * 32 + g * 8];
    }
    #pragma unroll
    for (int ks = 0; ks < 2; ++ks) {
        w2f0[ks] = *(const short8*)&W2b[(ch * 32 +      l15) * 72 + ks * 32 + g * 8];
        w2f1[ks] = *(const short8*)&W2b[(ch * 32 + 16 + l15) * 72 + ks * 32 + g * 8];
    }
    float4 wrv[2], b1v[2], b2v[2];
    {
        const float* Wr = &We1[((size_t)layer * 129 + 128) * 64];
        const float* B1 = &be1[layer * 64];
        const float* B2 = &be2[layer * 64];
        #pragma unroll
        for (int nt = 0; nt < 2; ++nt) {
            int n0 = ch * 32 + nt * 16 + g * 4;
            wrv[nt] = *(const float4*)&Wr[n0];
            b1v[nt] = *(const float4*)&B1[n0];
            b2v[nt] = *(const float4*)&B2[n0];
        }
    }

    const int* const ip = half ? eSrc : eDst;
    const int ebase = w * 16 + er;       // + i*4 ; (ebase+i*4)&7 == row&7

    // ---- prologue: gather tile0; prefetch idx(t1); stage(t0 -> LDS, t1 -> regs) ----
    int nid[4];
    {
        const int gb0 = tile0 * 64;
        #pragma unroll
        for (int i = 0; i < 4; ++i) nid[i] = ip[gb0 + ebase + i * 4];
        #pragma unroll
        for (int i = 0; i < 4; ++i)
            gload_lds16(&xbf[(size_t)nid[i] * 64 + ((c ^ ((ebase + i * 4) & 7)) << 3)],
                        xls0 + w * 2048 + i * 512);
        __builtin_amdgcn_sched_barrier(0);
        #pragma unroll
        for (int i = 0; i < 4; ++i) nid[i] = ip[gb0 + 64 + ebase + i * 4];
        if (t < 64) { sS[0][t] = eSrc[gb0 + t]; sD[0][t] = eDst[gb0 + t]; s2[0][t] = eD2[gb0 + t]; }
    }
    int stS = 0, stD = 0; float st2 = 0.f;
    if (t < 64) {
        const int gb1 = (tile0 + 1) * 64;
        stS = eSrc[gb1 + t]; stD = eDst[gb1 + t]; st2 = eD2[gb1 + t];
    }
    float bp2v = 0.f;
    if (POS) { bp2v = bp2[layer]; if (t < 64) sC[t] = bp2v; }
    VMDRAIN();      // tile0 gather landed
    FENCE_BAR();    // stage LDS visible; all waves ready

    const f32x4 zero = {0.f, 0.f, 0.f, 0.f};

    for (int tt = 0; tt < TPB; ++tt) {
        const int b = tt & 1;
        unsigned short* const xcur = b ? xls1 : xls0;
        unsigned short* const xnxt = b ? xls0 : xls1;

        // (top) issue gather(t+1); refill nid(t+2)
        if (tt + 1 < TPB) {
            #pragma unroll
            for (int i = 0; i < 4; ++i)
                gload_lds16(&xbf[(size_t)nid[i] * 64 + ((c ^ ((ebase + i * 4) & 7)) << 3)],
                            xnxt + w * 2048 + i * 512);
            __builtin_amdgcn_sched_barrier(0);
            if (tt + 2 < TPB) {
                const int gb2 = (tile0 + tt + 2) * 64;
                #pragma unroll
                for (int i = 0; i < 4; ++i) nid[i] = ip[gb2 + ebase + i * 4];
            }
        }

        // GEMM1: D^T[n][e], K=128 (xcur ready via previous end-of-iter barrier)
        f32x4 a00 = zero, a01 = zero, a10 = zero, a11 = zero;
        {
            const int r0 = (eh * 32 + l15) * 128;
            const int r1 = r0 + 16 * 128;
            const int r7 = l15 & 7;
            #pragma unroll
            for (int ks = 0; ks < 4; ++ks) {
                int col = (((ks << 2) + g) ^ r7) << 3;
                short8 fb0 = *(const short8*)&xcur[r0 + col];
                short8 fb1 = *(const short8*)&xcur[r1 + col];
                a00 = __builtin_amdgcn_mfma_f32_16x16x32_bf16(w1f0[ks], fb0, a00, 0, 0, 0);
                a01 = __builtin_amdgcn_mfma_f32_16x16x32_bf16(w1f0[ks], fb1, a01, 0, 0, 0);
                a10 = __builtin_amdgcn_mfma_f32_16x16x32_bf16(w1f1[ks], fb0, a10, 0, 0, 0);
                a11 = __builtin_amdgcn_mfma_f32_16x16x32_bf16(w1f1[ks], fb1, a11, 0, 0, 0);
            }
        }
        // ep1: + d2 row + bias, SiLU, quantize -> m1l
        {
            float d2e0 = s2[b][eh * 32 + l15];
            float d2e1 = s2[b][eh * 32 + 16 + l15];
            int e0 = eh * 32 + l15;
            int e1 = e0 + 16;
            #pragma unroll
            for (int nt = 0; nt < 2; ++nt) {
                int n0 = ch * 32 + nt * 16 + g * 4;
                float4 wr = wrv[nt], bb = b1v[nt];
                f32x4 acc0 = nt ? a10 : a00;
                f32x4 acc1 = nt ? a11 : a01;
                float r0 = silu_f(acc0.x + d2e0 * wr.x + bb.x);
                float r1 = silu_f(acc0.y + d2e0 * wr.y + bb.y);
                float r2 = silu_f(acc0.z + d2e0 * wr.z + bb.z);
                float r3 = silu_f(acc0.w + d2e0 * wr.w + bb.w);
                *(uint2*)&m1l[e0 * 72 + n0] = make_uint2(pk2(r0, r1), pk2(r2, r3));
                r0 = silu_f(acc1.x + d2e1 * wr.x + bb.x);
                r1 = silu_f(acc1.y + d2e1 * wr.y + bb.y);
                r2 = silu_f(acc1.z + d2e1 * wr.z + bb.z);
                r3 = silu_f(acc1.w + d2e1 * wr.w + bb.w);
                *(uint2*)&m1l[e1 * 72 + n0] = make_uint2(pk2(r0, r1), pk2(r2, r3));
            }
        }
        FENCE_BAR();   // (E): m1l written

        // GEMM2: K=64
        f32x4 c00 = zero, c01 = zero, c10 = zero, c11 = zero;
        #pragma unroll
        for (int ks = 0; ks < 2; ++ks) {
            short8 fb0 = *(const short8*)&m1l[(eh * 32 +      l15) * 72 + ks * 32 + g * 8];
            short8 fb1 = *(const short8*)&m1l[(eh * 32 + 16 + l15) * 72 + ks * 32 + g * 8];
            c00 = __builtin_amdgcn_mfma_f32_16x16x32_bf16(w2f0[ks], fb0, c00, 0, 0, 0);
            c01 = __builtin_amdgcn_mfma_f32_16x16x32_bf16(w2f0[ks], fb1, c01, 0, 0, 0);
            c10 = __builtin_amdgcn_mfma_f32_16x16x32_bf16(w2f1[ks], fb0, c10, 0, 0, 0);
            c11 = __builtin_amdgcn_mfma_f32_16x16x32_bf16(w2f1[ks], fb1, c11, 0, 0, 0);
        }
        FENCE_BAR();   // (F): m1l readers done -> sM2f overlay safe

        // ep2: + bias, SiLU -> sM2f; stage-write tile t+1; refill stage regs (t+2)
        {
            int e0 = eh * 32 + l15;
            int e1 = e0 + 16;
            #pragma unroll
            for (int nt = 0; nt < 2; ++nt) {
                int n0 = ch * 32 + nt * 16 + g * 4;
                float4 bb = b2v[nt];
                f32x4 acc0 = nt ? c10 : c00;
                f32x4 acc1 = nt ? c11 : c01;
                sM2f[e0 * 65 + n0 + 0] = silu_f(acc0.x + bb.x);
                sM2f[e0 * 65 + n0 + 1] = silu_f(acc0.y + bb.y);
                sM2f[e0 * 65 + n0 + 2] = silu_f(acc0.z + bb.z);
                sM2f[e0 * 65 + n0 + 3] = silu_f(acc0.w + bb.w);
                sM2f[e1 * 65 + n0 + 0] = silu_f(acc1.x + bb.x);
                sM2f[e1 * 65 + n0 + 1] = silu_f(acc1.y + bb.y);
                sM2f[e1 * 65 + n0 + 2] = silu_f(acc1.z + bb.z);
                sM2f[e1 * 65 + n0 + 3] = silu_f(acc1.w + bb.w);
            }
        }
        if (tt + 1 < TPB && t < 64) {
            sS[1 - b][t] = stS; sD[1 - b][t] = stD; s2[1 - b][t] = st2;
            if (tt + 2 < TPB) {
                const int gb2 = (tile0 + tt + 2) * 64;
                stS = eSrc[gb2 + t]; stD = eDst[gb2 + t]; st2 = eD2[gb2 + t];
            }
        }
        FENCE_BAR();   // (G): sM2f + next-tile stage visible

        if (POS) {
            const int wofs = __builtin_amdgcn_readfirstlane(w * 16);
            float p1[16];
            {
                const float* bP1 = &bp1[(size_t)layer * 64 + wofs];
                #pragma unroll
                for (int hh = 0; hh < 16; ++hh) p1[hh] = bP1[hh];
            }
            const float* P1 = &Wp1[(size_t)layer * 64 * 64 + wofs];
            for (int k = 0; k < 64; ++k) {
                float mv = sM2f[lane * 65 + k];
                const float* wr2 = P1 + k * 64;
                #pragma unroll
                for (int hh = 0; hh < 16; ++hh) p1[hh] = fmaf(mv, wr2[hh], p1[hh]);
            }
            float part = 0.0f;
            {
                const float* P2 = &Wp2[(size_t)layer * 64 + wofs];
                #pragma unroll
                for (int hh = 0; hh < 16; ++hh) part += silu_f(p1[hh]) * P2[hh];
            }
            atomicAdd(&sC[lane], part);
            FENCE_BAR();   // (H): sC complete
            if (w == 0) {
                float cc = sC[lane];
                int d = sD[b][lane], s = sS[b][lane];
                float rx = pos[3*d+0] - pos[3*s+0];
                float ry = pos[3*d+1] - pos[3*s+1];
                float rz = pos[3*d+2] - pos[3*s+2];
                atomicAdd(&dpos[3*(size_t)d+0], rx * cc);
                atomicAdd(&dpos[3*(size_t)d+1], ry * cc);
                atomicAdd(&dpos[3*(size_t)d+2], rz * cc);
            }
            FENCE_BAR();   // (H2): sC consumers done
            if (t < 64) sC[t] = bp2v;   // re-init for next tile
        }

        // THE FIX: drain all vmem (incl. gather(t+1)) once per iteration, while
        // it has had the whole iteration to complete. Buffers flip at END bar.
        VMDRAIN();

        // scatter: wave w owns edges [w*16, w*16+16), lane = channel; reads unrolled
        {
            const int e0 = w * 16;
            float v[16];
            #pragma unroll
            for (int i = 0; i < 16; ++i) v[i] = sM2f[(e0 + i) * 65 + lane];
            int dd[16];
            #pragma unroll
            for (int i = 0; i < 16; ++i) dd[i] = sD[b][e0 + i];
            float run = v[0];
            int cur = dd[0];
            #pragma unroll
            for (int i = 1; i < 16; ++i) {
                if (dd[i] != cur) {
                    atomicAdd(&agg[(size_t)cur * 64 + lane], run);
                    run = 0.0f;
                    cur = dd[i];
                }
                run += v[i];
            }
            atomicAdd(&agg[(size_t)cur * 64 + lane], run);
        }
        FENCE_BAR();   // (END): scatter LDS reads drained; next iter may overwrite
    }
}

// ---------------- node MLP (fp32 VALU) + bf16 x export ----------------
__global__ __launch_bounds__(256) void egnn_node(
    const float* __restrict__ x, const float* __restrict__ agg,
    const float* __restrict__ Wn1, const float* __restrict__ bn1,
    const float* __restrict__ Wn2, const float* __restrict__ bn2,
    float* __restrict__ xout, unsigned short* __restrict__ xbf_out, int layer)
{
    __shared__ float sX[64 * 65];
    __shared__ float sA[64 * 65];

    const int t    = threadIdx.x;
    const int w    = t >> 6;
    const int lane = t & 63;
    const int base = blockIdx.x * 64;
    const int nval = (NN - base < 64) ? (NN - base) : 64;
    const int wofs = __builtin_amdgcn_readfirstlane(w * 16);

    #pragma unroll
    for (int i = 0; i < 4; ++i) {
        int idx = i * 256 + t;
        int e = idx >> 4, c = idx & 15;
        if (e < nval) {
            const float4 vx = *reinterpret_cast<const float4*>(&x[(size_t)(base + e) * 64 + c * 4]);
            const float4 va = *reinterpret_cast<const float4*>(&agg[(size_t)(base + e) * 64 + c * 4]);
            float* px = &sX[e * 65 + c * 4];
            float* pa = &sA[e * 65 + c * 4];
            px[0]=vx.x; px[1]=vx.y; px[2]=vx.z; px[3]=vx.w;
            pa[0]=va.x; pa[1]=va.y; pa[2]=va.z; pa[3]=va.w;
        }
    }
    __syncthreads();

    float acc[16];
    {
        const float* b = &bn1[(size_t)layer * 64 + wofs];
        #pragma unroll
        for (int hh = 0; hh < 16; ++hh) acc[hh] = b[hh];
    }
    const float* W1 = &Wn1[(size_t)layer * 128 * 64 + wofs];
    for (int k = 0; k < 64; ++k) {
        float inv = sX[lane * 65 + k];
        const float* wr = W1 + k * 64;
        #pragma unroll
        for (int hh = 0; hh < 16; ++hh) acc[hh] = fmaf(inv, wr[hh], acc[hh]);
    }
    for (int k = 0; k < 64; ++k) {
        float inv = sA[lane * 65 + k];
        const float* wr = W1 + (64 + k) * 64;
        #pragma unroll
        for (int hh = 0; hh < 16; ++hh) acc[hh] = fmaf(inv, wr[hh], acc[hh]);
    }
    #pragma unroll
    for (int hh = 0; hh < 16; ++hh) acc[hh] = silu_f(acc[hh]);
    __syncthreads();
    #pragma unroll
    for (int hh = 0; hh < 16; ++hh) sA[lane * 65 + wofs + hh] = acc[hh];
    __syncthreads();

    float o[16];
    {
        const float* b = &bn2[(size_t)layer * 64 + wofs];
        #pragma unroll
        for (int hh = 0; hh < 16; ++hh) o[hh] = b[hh];
    }
    const float* W2 = &Wn2[(size_t)layer * 64 * 64 + wofs];
    for (int k = 0; k < 64; ++k) {
        float inv = sA[lane * 65 + k];
        const float* wr = W2 + k * 64;
        #pragma unroll
        for (int hh = 0; hh < 16; ++hh) o[hh] = fmaf(inv, wr[hh], o[hh]);
    }
    // bf16 export for next layer's edge gather (from regs, coalesced 16B)
    if (lane < nval) {
        uint4 u0, u1;
        u0.x = pk2(o[0], o[1]);   u0.y = pk2(o[2],  o[3]);
        u0.z = pk2(o[4], o[5]);   u0.w = pk2(o[6],  o[7]);
        u1.x = pk2(o[8], o[9]);   u1.y = pk2(o[10], o[11]);
        u1.z = pk2(o[12], o[13]); u1.w = pk2(o[14], o[15]);
        *(uint4*)&xbf_out[(size_t)(base + lane) * 64 + wofs + 0] = u0;
        *(uint4*)&xbf_out[(size_t)(base + lane) * 64 + wofs + 8] = u1;
    }
    #pragma unroll
    for (int hh = 0; hh < 16; ++hh) sX[lane * 65 + wofs + hh] = o[hh];
    __syncthreads();
    #pragma unroll
    for (int i = 0; i < 4; ++i) {
        int idx = i * 256 + t;
        int e = idx >> 4, c = idx & 15;
        if (e < nval) {
            float4 v;
            const float* p = &sX[e * 65 + c * 4];
            v.x = p[0]; v.y = p[1]; v.z = p[2]; v.w = p[3];
            *reinterpret_cast<float4*>(&xout[(size_t)(base + e) * 64 + c * 4]) = v;
        }
    }
}

// ---------------- finalize positions ----------------
__global__ __launch_bounds__(256) void egnn_final(
    const float* __restrict__ pos, const float* __restrict__ dpos,
    const int* __restrict__ rowptr, const float* __restrict__ logit,
    float* __restrict__ pos_out)
{
    int i = blockIdx.x * 256 + threadIdx.x;
    if (i >= NN * 3) return;
    int node = i / 3;
    float dg = fmaxf((float)(rowptr[node + 1] - rowptr[node]), 1.0f);
    float sig = 1.0f / (1.0f + __expf(-logit[0]));
    float upd = (dpos[i] / dg) * sig;
    upd = fminf(fmaxf(upd, -5.0f), 5.0f);
    float p = pos[i] + upd;
    pos_out[i] = fminf(fmaxf(p, -500.0f), 500.0f);
}

extern "C" void kernel_launch(void* const* d_in, const int* in_sizes, int n_in,
                              void* d_out, int out_size, void* d_ws, size_t ws_size,
                              hipStream_t stream)
{
    const float* x0    = (const float*)d_in[0];
    const float* pos   = (const float*)d_in[1];
    const int*   src   = (const int*)d_in[2];
    const int*   dst   = src + NE;
    const float* We1   = (const float*)d_in[3];
    const float* be1   = (const float*)d_in[4];
    const float* We2   = (const float*)d_in[5];
    const float* be2   = (const float*)d_in[6];
    const float* Wn1   = (const float*)d_in[7];
    const float* bn1   = (const float*)d_in[8];
    const float* Wn2   = (const float*)d_in[9];
    const float* bn2   = (const float*)d_in[10];
    const float* Wp1   = (const float*)d_in[11];
    const float* bp1   = (const float*)d_in[12];
    const float* Wp2   = (const float*)d_in[13];
    const float* bp2   = (const float*)d_in[14];
    const float* logit = (const float*)d_in[15];

    float* xout    = (float*)d_out;                 // [NN,64]
    float* pos_out = xout + (size_t)NN * 64;        // [NN,3]

    float* ws  = (float*)d_ws;
    float* xA   = ws;  ws += (size_t)NN * 64;       // fp32 x ping
    float* agg  = ws;  ws += (size_t)NN * 64;
    float* dpos = ws;  ws += (size_t)NN * 3;
    float* eD2  = ws;  ws += NE;
    int* rowptr = (int*)ws;  ws += NN + 1;
    int* hc     = (int*)ws;  ws += NN;              // hist -> cursor
    int* eSrc   = (int*)ws;  ws += NE;
    int* eDst   = (int*)ws;  ws += NE;
    unsigned short* xbf = (unsigned short*)ws;      // [NN,64] bf16
    ws += (size_t)NN * 32;                          // NN*64 ushorts = NN*32 floats
    unsigned short* Wg1 = (unsigned short*)ws;      // 4*64*136 bf16
    unsigned short* Wg2 = Wg1 + 4 * 64 * 136;       // 4*64*72 bf16

    hipMemsetAsync(hc, 0, NN * sizeof(int), stream);
    hipMemsetAsync(dpos, 0, (size_t)NN * 3 * sizeof(float), stream);
    egnn_hist<<<NE / 256, 256, 0, stream>>>(dst, hc);
    egnn_scan<<<1, 1024, 0, stream>>>(hc, rowptr);
    egnn_scatter<<<NE / 256, 256, 0, stream>>>(src, dst, pos, hc, eSrc, eDst, eD2);
    egnn_prep_w<<<128, 256, 0, stream>>>(We1, We2, Wg1, Wg2);
    egnn_xbf<<<(NN * 16 + 255) / 256, 256, 0, stream>>>(x0, xbf);

    const int nblk = NE / 64 / TPB;                 // 1250
    const float* xin = x0;
    for (int l = 0; l < 4; ++l) {
        hipMemsetAsync(agg, 0, (size_t)NN * 64 * sizeof(float), stream);
        if (l == 3) {
            egnn_edge<true><<<nblk, 256, 0, stream>>>(
                xbf, eD2, eSrc, eDst, pos, Wg1, Wg2, We1, be1, be2,
                Wp1, bp1, Wp2, bp2, agg, dpos, l);
        } else {
            egnn_edge<false><<<nblk, 256, 0, stream>>>(
                xbf, eD2, eSrc, eDst, pos, Wg1, Wg2, We1, be1, be2,
                Wp1, bp1, Wp2, bp2, agg, dpos, l);
        }
        float* xo = (l % 2 == 0) ? xA : xout;       // l0->xA, l1->xout, l2->xA, l3->xout
        egnn_node<<<(NN + 63) / 64, 256, 0, stream>>>(xin, agg, Wn1, bn1, Wn2, bn2, xo, xbf, l);
        xin = xo;
    }
    egnn_final<<<(NN * 3 + 255) / 256, 256, 0, stream>>>(pos, dpos, rowptr, logit, pos_out);
}